// Round 18
// baseline (215.701 us; speedup 1.0000x reference)
//
#include <hip/hip_runtime.h>
#include <hip/hip_bf16.h>
#include <stdint.h>

// B=8, N=1024, I=256, O=256, R=8
// out[b,dst,o] = (sum_{src,r} adj[b,src,dst,r] * f[b,src,r,o]) / clip(sum adj, 1e-16)
//
//  prep : x fp32->bf16; weight -> W_t[o*8+r][i] bf16
//  k1   : f_t[b][o][k=src*8+r] = W_t @ x^T (8B vector stores)
//  k2   : pout = adj^T @ f_t. MT=32 x NT=128, KS=2 -> 1024 blocks x 256 thr
//         (4 waves = 4 o-quarters), KT=64, 4 blocks/CU (LDS 8KB only).
//         R17->R18: NO vmcnt at any barrier. Operands assigned by residency:
//         A (adj, HBM) -> coalesced reg-load -> cvt -> ds_write -> LDS (shared
//         across the 4 o-waves); B (f_t, L2-resident) -> DIRECT global->register
//         MFMA fragments (16B/lane; L1 completes sectors). Barrier fence =
//         lgkmcnt(0) only; every global load waits at its consumer via
//         compiler-tracked counted vmcnt (never drains newer prefetches).
//         A: 3 reg sets, load kt+3, store kt+1 (2-step HBM cover, wait-free).
//         B: 2 reg sets, load kt+1 (1-step cover >> L2 latency). 6-step macro.
//         R15's counted-fence structure plateaued at k2~105us across three
//         scheduling levers (R15/16/17) -> the vmcnt-FIFO/barrier coupling was
//         the invariant; this removes it.
//  k3   : sum split-K partials, normalize.

typedef float          floatx4  __attribute__((ext_vector_type(4)));
typedef short          shortx8  __attribute__((ext_vector_type(8)));
typedef unsigned short ushortx4 __attribute__((ext_vector_type(4)));
typedef unsigned short ushortx8 __attribute__((ext_vector_type(8)));

__device__ __forceinline__ unsigned short f2bf(float f) {   // native RNE cast
  __hip_bfloat16 h = __float2bfloat16(f);
  unsigned short u; __builtin_memcpy(&u, &h, 2);
  return u;
}

// ---------------- merged prep ----------------
__global__ __launch_bounds__(256) void prep_xw(const float* __restrict__ x,
                                               const float* __restrict__ w,
                                               unsigned short* __restrict__ xbf,
                                               unsigned short* __restrict__ wt) {
  int bid = blockIdx.x;
  if (bid < 1024) {                                // x: 262144 threads x 8 elems
    int t = bid * 256 + threadIdx.x;
    const float4* p = (const float4*)x + (size_t)t * 2;
    float4 a = p[0], b4 = p[1];
    ushortx8 o;
    o[0] = f2bf(a.x);  o[1] = f2bf(a.y);  o[2] = f2bf(a.z);  o[3] = f2bf(a.w);
    o[4] = f2bf(b4.x); o[5] = f2bf(b4.y); o[6] = f2bf(b4.z); o[7] = f2bf(b4.w);
    *(ushortx8*)(xbf + (size_t)t * 8) = o;
  } else {                                         // w: 524288 scalar
    int id = (bid - 1024) * 256 + threadIdx.x;
    int r = id >> 16, i = (id >> 8) & 255, o = id & 255;
    float v = w[((size_t)(r * 256 + i) << 8) + o];
    wt[((size_t)(o * 8 + r) << 8) + i] = f2bf(v);
  }
}

// ---------------- kernel 1: f_t = x @ W (operand-swapped) ----------------
__global__ __launch_bounds__(256) void k1_gemm(const unsigned short* __restrict__ xbf,
                                               const unsigned short* __restrict__ wt,
                                               unsigned short* __restrict__ ft) {
  int bid = blockIdx.x;                            // 16 p-tiles x 64 q-tiles
  int p0 = (bid & 15) * 128, q0 = (bid >> 4) * 128;
  int l = threadIdx.x & 63, w = threadIdx.x >> 6;
  int lr = l & 15, lg = l >> 4;
  int pw = p0 + (w >> 1) * 64, qw = q0 + (w & 1) * 64;

  floatx4 acc[4][4] = {};
#pragma unroll
  for (int ks = 0; ks < 8; ++ks) {                 // K = 256 = 8 * 32
    shortx8 a[4], b[4];
#pragma unroll
    for (int pi = 0; pi < 4; ++pi)
      a[pi] = *(const shortx8*)(wt + (size_t)(pw + pi * 16 + lr) * 256 + ks * 32 + lg * 8);
#pragma unroll
    for (int qi = 0; qi < 4; ++qi)
      b[qi] = *(const shortx8*)(xbf + (size_t)(qw + qi * 16 + lr) * 256 + ks * 32 + lg * 8);
#pragma unroll
    for (int pi = 0; pi < 4; ++pi)
#pragma unroll
      for (int qi = 0; qi < 4; ++qi)
        acc[pi][qi] = __builtin_amdgcn_mfma_f32_16x16x32_bf16(a[pi], b[qi], acc[pi][qi], 0, 0, 0);
  }
  // row(n') = pw+pi*16+lg*4+reg -> (o, r); col(m) = qw+qi*16+lr -> (b8, src)
#pragma unroll
  for (int pi = 0; pi < 4; ++pi) {
    int nbase = pw + pi * 16 + lg * 4;
    int o = nbase >> 3, rb = nbase & 7;
#pragma unroll
    for (int qi = 0; qi < 4; ++qi) {
      int m = qw + qi * 16 + lr;
      int b8 = m >> 10, src = m & 1023;
      ushortx4 h;
      h[0] = f2bf(acc[pi][qi][0]); h[1] = f2bf(acc[pi][qi][1]);
      h[2] = f2bf(acc[pi][qi][2]); h[3] = f2bf(acc[pi][qi][3]);
      *(ushortx4*)(ft + ((size_t)(b8 * 256 + o) << 13) + src * 8 + rb) = h;
    }
  }
}

// ---------------- kernel 2: pout = adj^T @ f_t (+ denom) ----------------
// 1024 blocks x 256 thr (4 waves = 4 o-quarters). Block: b, 32 dst, 128 o, K-half.
#define ASZ (32 * 64)     // shorts per A buffer (4KB), x2
__global__ __launch_bounds__(256, 4) void k2_gemm(const float* __restrict__ adj,
                                                  const unsigned short* __restrict__ ft,
                                                  float* __restrict__ pout,
                                                  float* __restrict__ dpart) {
  __shared__ __align__(16) unsigned short Alds[2 * ASZ];  // 8KB total

  int bid = blockIdx.x;                // [dst(5)|kc(1)|o(1)|b(3)]
  int b = bid & 7;                     // XCD pin; (bid,bid+8) o-sharers same XCD
  int o0 = ((bid >> 3) & 1) * 128;
  int kc = (bid >> 4) & 1;
  int dst0 = (bid >> 5) * 32;

  int t = threadIdx.x, l = t & 63, w = t >> 6;     // 4 waves, wave = o-quarter
  int lr = l & 15, lg = l >> 4;
  bool wq0 = (w == 0);

  const int src_base = kc * 512;
  const size_t adj_b = (size_t)b << 23;
  const unsigned short* ftb = ft + ((size_t)b << 21);

  // A-staging (coalesced): thread -> dst_l (0..31), r-half, 2 src rows (sA, sA+4)
  int dst_l = (t >> 1) & 31;
  int rh = (t & 1) * 4;
  int sA = t >> 6;                     // 0..3

  float dsum = 0.f;
  floatx4 acc[2][2] = {};
  float4 a0[2], a1[2], a2[2];          // A fp32 in flight, 3 sets
  shortx8 bs0[2][2], bs1[2][2];        // B frags [ni][s], 2 sets

  auto A_load = [&](int kt, float4* v) {
#pragma unroll
    for (int j = 0; j < 2; ++j) {
      int src = src_base + kt * 8 + sA + j * 4;
      v[j] = *(const float4*)(adj + adj_b + ((size_t)src << 13)
                              + ((size_t)(dst0 + dst_l) << 3) + rh);
    }
  };
  auto A_store = [&](int abuf, const float4* v) {
#pragma unroll
    for (int j = 0; j < 2; ++j) {
      int src_l = sA + j * 4;
      float4 q = v[j];
      dsum += q.x + q.y + q.z + q.w;
      ushortx4 h;
      h[0] = f2bf(q.x); h[1] = f2bf(q.y); h[2] = f2bf(q.z); h[3] = f2bf(q.w);
      int slot = src_l ^ (dst_l & 7);
      *(ushortx4*)&Alds[abuf * ASZ + dst_l * 64 + slot * 8 + rh] = h;
    }
  };
  auto B_load = [&](int kt, shortx8 (&v)[2][2]) {  // direct global->reg frags
    int kbase = (src_base + kt * 8) * 8;
#pragma unroll
    for (int ni = 0; ni < 2; ++ni)
#pragma unroll
      for (int s = 0; s < 2; ++s) {
        int orow = o0 + w * 32 + ni * 16 + lr;
        v[ni][s] = *(const shortx8*)(ftb + ((size_t)orow << 13) + kbase + (s * 4 + lg) * 8);
      }
  };
  auto compute = [&](int abuf, shortx8 (&bv)[2][2]) {
#pragma unroll
    for (int s = 0; s < 2; ++s) {
      int slotbase = s * 4 + lg;
      shortx8 af[2];
#pragma unroll
      for (int mi = 0; mi < 2; ++mi) {
        int arow = mi * 16 + lr;
        af[mi] = *(const shortx8*)&Alds[abuf * ASZ + arow * 64 + ((slotbase ^ (arow & 7)) << 3)];
      }
#pragma unroll
      for (int mi = 0; mi < 2; ++mi)
#pragma unroll
        for (int ni = 0; ni < 2; ++ni)
          acc[mi][ni] = __builtin_amdgcn_mfma_f32_16x16x32_bf16(af[mi], bv[ni][s], acc[mi][ni], 0, 0, 0);
    }
  };

// step kt: A_load(kt+3)->ALD; B_load(kt+1)->BLD; A_store tile kt+1 (AST, loaded
// step kt-2, wait-free reg-dep); compute(buf kt&1, BCP = B(kt)); lgkm-only barrier.
#define STEP(kt, CUR, NXT, ALD, AST, BLD, BCP, ISSA, ISSB, STA, BAR)   \
  {                                                                    \
    if (ISSA) A_load((kt) + 3, ALD);                                   \
    if (ISSB) B_load((kt) + 1, BLD);                                   \
    if (STA) A_store(NXT, AST);                                        \
    compute(CUR, BCP);                                                 \
    if (BAR) {                                                         \
      asm volatile("s_waitcnt lgkmcnt(0)" ::: "memory");               \
      __builtin_amdgcn_s_barrier();                                    \
      asm volatile("" ::: "memory");                                   \
    }                                                                  \
  }

  // ---- prologue: A(0..2) in reg sets, B(0) in bs0; store A(0)->buf0 ----
  A_load(0, a0);
  A_load(1, a1);
  A_load(2, a2);
  B_load(0, bs0);
  A_store(0, a0);                      // waits only its own loads (reg dep)
  asm volatile("s_waitcnt lgkmcnt(0)" ::: "memory");
  __builtin_amdgcn_s_barrier();
  asm volatile("" ::: "memory");

  // ---- main loop: kt 0..59 in 6-step macro (A-sets 3 x buf/B-sets 2) ----
  for (int kt0 = 0; kt0 < 60; kt0 += 6) {
    STEP(kt0 + 0, 0, 1, a0, a1, bs1, bs0, 1, 1, 1, 1);
    STEP(kt0 + 1, 1, 0, a1, a2, bs0, bs1, 1, 1, 1, 1);
    STEP(kt0 + 2, 0, 1, a2, a0, bs1, bs0, 1, 1, 1, 1);
    STEP(kt0 + 3, 1, 0, a0, a1, bs0, bs1, 1, 1, 1, 1);
    STEP(kt0 + 4, 0, 1, a1, a2, bs1, bs0, 1, 1, 1, 1);
    STEP(kt0 + 5, 1, 0, a2, a0, bs0, bs1, 1, 1, 1, 1);
  }
  // ---- tail: kt 60..63 (last A tile 63 loaded at kt=60; last B at kt=62) ----
  STEP(60, 0, 1, a0, a1, bs1, bs0, 1, 1, 1, 1);
  STEP(61, 1, 0, a1, a2, bs0, bs1, 0, 1, 1, 1);
  STEP(62, 0, 1, a2, a0, bs1, bs0, 0, 1, 1, 1);   // stores tile 63 (set a0)
  STEP(63, 1, 0, a0, a1, bs0, bs1, 0, 0, 0, 0);
#undef STEP
  __syncthreads();                     // protect Alds overlay (full drain, once)

  // ---- denom reduction (deterministic): 8 partials per dst row ----
  float* dsf = (float*)Alds;
  dsf[t] = dsum;
  __syncthreads();
  if (t < 32) {
    float s = 0.f;
#pragma unroll
    for (int sl = 0; sl < 4; ++sl) {
      s += dsf[sl * 64 + t * 2];
      s += dsf[sl * 64 + t * 2 + 1];
    }
    dpart[kc * 8192 + (b << 10) + dst0 + t] = s;
  }

  // ---- write partials ----
#pragma unroll
  for (int mi = 0; mi < 2; ++mi) {
#pragma unroll
    for (int reg = 0; reg < 4; ++reg) {
      int row = dst0 + mi * 16 + lg * 4 + reg;
#pragma unroll
      for (int ni = 0; ni < 2; ++ni) {
        int col = o0 + w * 32 + ni * 16 + lr;
        pout[(size_t)kc * 2097152 + (((size_t)b << 10) + row) * 256 + col] = acc[mi][ni][reg];
      }
    }
  }
}

// ---------------- kernel 3: split-K reduce + normalize ----------------
__global__ __launch_bounds__(256) void k3_reduce(const float* __restrict__ pout,
                                                 const float* __restrict__ dpart,
                                                 float* __restrict__ outp) {
  int bid = blockIdx.x;              // b*1024 + dst
  size_t base = (size_t)bid * 256 + threadIdx.x;
  float v = pout[base] + pout[2097152 + base];
  float d = dpart[bid] + dpart[8192 + bid];
  outp[base] = v / fmaxf(d, 1e-16f);
}

// ---------------- launch ----------------
extern "C" void kernel_launch(void* const* d_in, const int* in_sizes, int n_in,
                              void* d_out, int out_size, void* d_ws, size_t ws_size,
                              hipStream_t stream) {
  const float* x   = (const float*)d_in[0];
  const float* adj = (const float*)d_in[1];
  const float* w   = (const float*)d_in[2];
  float* out = (float*)d_out;

  char* ws = (char*)d_ws;
  unsigned short* ft  = (unsigned short*)(ws);              // 32 MB
  unsigned short* xbf = (unsigned short*)(ws + 33554432);   //  4 MB
  unsigned short* wt  = (unsigned short*)(ws + 37748736);   //  1 MB
  float* pout  = (float*)(ws + 38797312);                   // 16 MB
  float* dpart = (float*)(ws + 55574528);                   // 64 KB

  prep_xw<<<3072, 256, 0, stream>>>(x, w, xbf, wt);
  k1_gemm<<<1024, 256, 0, stream>>>(xbf, wt, ft);
  k2_gemm<<<1024, 256, 0, stream>>>(adj, ft, pout, dpart);
  k3_reduce<<<8192, 256, 0, stream>>>(pout, dpart, out);
}